// Round 1
// baseline (83.318 us; speedup 1.0000x reference)
//
#include <hip/hip_runtime.h>

#define BB 512
#define NN 256
#define SS 128
#define MM 64
#define UNFOLDS 6
#define BT 8
#define JT 64

static constexpr float EPS_ = 1e-8f;
static constexpr float L2E = 1.4426950408889634f;

// ---------- precompute: fold params into float4 {a, c, wE, wm} ----------
// gate = 1 / (1 + exp2(a*v + c)),  a = -sigma*log2e, c = sigma*mu*log2e
__global__ __launch_bounds__(256) void prep_rec(
    const float* __restrict__ w, const float* __restrict__ sg,
    const float* __restrict__ mu, const float* __restrict__ E,
    const float* __restrict__ mask, float4* __restrict__ p) {
  int idx = blockIdx.x * 256 + threadIdx.x;
  if (idx >= NN * NN) return;
  float a = sg[idx] * L2E;
  float wm = w[idx] * mask[idx];
  p[idx] = make_float4(-a, a * mu[idx], wm * E[idx], wm);
}

// sensory: also fold input affine xt = x*iw[s] + ib[s] into (a,c)
__global__ __launch_bounds__(256) void prep_sens(
    const float* __restrict__ w, const float* __restrict__ sg,
    const float* __restrict__ mu, const float* __restrict__ E,
    const float* __restrict__ mask, const float* __restrict__ iw,
    const float* __restrict__ ib, float4* __restrict__ p) {
  int idx = blockIdx.x * 256 + threadIdx.x;
  if (idx >= SS * NN) return;
  int s = idx >> 8;  // idx / NN
  float a = sg[idx] * L2E;
  float wm = w[idx] * mask[idx];
  // -a*(x*iw+ib) + a*mu = (-a*iw)*x + a*(mu - ib)
  p[idx] = make_float4(-a * iw[s], a * (mu[idx] - ib[s]), wm * E[idx], wm);
}

// ---------- sensory aggregation: (B,S,N) -> snum/sden (B,N) ----------
__global__ __launch_bounds__(512) void sensory_kernel(
    const float* __restrict__ x, const float4* __restrict__ ps,
    float* __restrict__ snum, float* __restrict__ sden) {
  __shared__ float xt[BT][SS];
  __shared__ float4 red[256];
  int tid = threadIdx.x;
  int bbase = blockIdx.x * BT;
  int jbase = blockIdx.y * JT;
  // stage x tile: BT*SS = 1024 floats, 512 threads -> 2 each
  for (int k = 0; k < 2; ++k) {
    int idx = tid + k * 512;
    xt[idx >> 7][idx & 127] = x[(bbase + (idx >> 7)) * SS + (idx & 127)];
  }
  __syncthreads();
  int j = tid & 63;
  int g = (tid >> 6) & 3;
  int half = tid >> 8;
  int b0 = 2 * g, b1 = b0 + 1;
  float n0 = 0, d0 = 0, n1 = 0, d1 = 0;
  int s0 = half * (SS / 2);
#pragma unroll 8
  for (int ss = 0; ss < SS / 2; ++ss) {
    int s = s0 + ss;
    float4 p = ps[s * NN + jbase + j];
    float v0 = xt[b0][s], v1 = xt[b1][s];
    float e0 = __builtin_amdgcn_exp2f(fmaf(p.x, v0, p.y));
    float e1 = __builtin_amdgcn_exp2f(fmaf(p.x, v1, p.y));
    float g0 = __builtin_amdgcn_rcpf(1.0f + e0);
    float g1 = __builtin_amdgcn_rcpf(1.0f + e1);
    n0 = fmaf(p.z, g0, n0); d0 = fmaf(p.w, g0, d0);
    n1 = fmaf(p.z, g1, n1); d1 = fmaf(p.w, g1, d1);
  }
  int t = tid & 255;
  if (half) red[t] = make_float4(n0, d0, n1, d1);
  __syncthreads();
  if (!half) {
    float4 r = red[t];
    n0 += r.x; d0 += r.y; n1 += r.z; d1 += r.w;
    int jg = jbase + j;
    snum[(bbase + b0) * NN + jg] = n0; sden[(bbase + b0) * NN + jg] = d0;
    snum[(bbase + b1) * NN + jg] = n1; sden[(bbase + b1) * NN + jg] = d1;
  }
}

// ---------- one ODE unfold ----------
__global__ __launch_bounds__(512) void unfold_kernel(
    const float* __restrict__ vin, const float4* __restrict__ pr,
    const float* __restrict__ snum, const float* __restrict__ sden,
    const float* __restrict__ gl, const float* __restrict__ rp,
    const float* __restrict__ cap, float* __restrict__ vout,
    const float* __restrict__ ow, const float* __restrict__ ob,
    float* __restrict__ out, int last) {
  __shared__ float vt[BT][NN];   // 8 KiB
  __shared__ float4 red[256];    // 4 KiB
  int tid = threadIdx.x;
  int bbase = blockIdx.x * BT;
  int jbase = blockIdx.y * JT;
  // stage v tile: BT*NN = 2048 floats, 512 threads -> 4 each
  for (int k = 0; k < 4; ++k) {
    int idx = tid + k * 512;
    vt[idx >> 8][idx & 255] = vin[(bbase + (idx >> 8)) * NN + (idx & 255)];
  }
  __syncthreads();
  int j = tid & 63;
  int g = (tid >> 6) & 3;
  int half = tid >> 8;
  int b0 = 2 * g, b1 = b0 + 1;
  float n0 = 0, d0 = 0, n1 = 0, d1 = 0;
  int i0 = half * (NN / 2);
#pragma unroll 8
  for (int ii = 0; ii < NN / 2; ++ii) {
    int i = i0 + ii;
    float4 p = pr[i * NN + jbase + j];
    float v0 = vt[b0][i], v1 = vt[b1][i];
    float e0 = __builtin_amdgcn_exp2f(fmaf(p.x, v0, p.y));
    float e1 = __builtin_amdgcn_exp2f(fmaf(p.x, v1, p.y));
    float g0 = __builtin_amdgcn_rcpf(1.0f + e0);
    float g1 = __builtin_amdgcn_rcpf(1.0f + e1);
    n0 = fmaf(p.z, g0, n0); d0 = fmaf(p.w, g0, d0);
    n1 = fmaf(p.z, g1, n1); d1 = fmaf(p.w, g1, d1);
  }
  int t = tid & 255;
  if (half) red[t] = make_float4(n0, d0, n1, d1);
  __syncthreads();
  if (!half) {
    float4 r = red[t];
    n0 += r.x; d0 += r.y; n1 += r.z; d1 += r.w;
    int jg = jbase + j;
    float cmt = cap[jg] * (float)UNFOLDS;  // cap / (ELAPSED/UNFOLDS)
    float glv = gl[jg];
    float base = glv * rp[jg];
    int i0g = (bbase + b0) * NN + jg;
    int i1g = (bbase + b1) * NN + jg;
    float num0 = fmaf(cmt, vt[b0][jg], base) + n0 + snum[i0g];
    float den0 = cmt + glv + d0 + sden[i0g] + EPS_;
    float vn0 = num0 / den0;
    float num1 = fmaf(cmt, vt[b1][jg], base) + n1 + snum[i1g];
    float den1 = cmt + glv + d1 + sden[i1g] + EPS_;
    float vn1 = num1 / den1;
    vout[i0g] = vn0;
    vout[i1g] = vn1;
    if (last && jbase == 0) {  // jg < MM exactly when jbase==0 (JT==MM)
      out[(bbase + b0) * MM + jg] = fmaf(vn0, ow[jg], ob[jg]);
      out[(bbase + b1) * MM + jg] = fmaf(vn1, ow[jg], ob[jg]);
    }
  }
}

extern "C" void kernel_launch(void* const* d_in, const int* in_sizes, int n_in,
                              void* d_out, int out_size, void* d_ws, size_t ws_size,
                              hipStream_t stream) {
  const float* x     = (const float*)d_in[0];
  const float* state = (const float*)d_in[1];
  const float* gl    = (const float*)d_in[2];
  const float* rp    = (const float*)d_in[3];
  const float* cap   = (const float*)d_in[4];
  const float* w     = (const float*)d_in[5];
  const float* sg    = (const float*)d_in[6];
  const float* mu    = (const float*)d_in[7];
  const float* E     = (const float*)d_in[8];
  const float* sw    = (const float*)d_in[9];
  const float* ssg   = (const float*)d_in[10];
  const float* smu   = (const float*)d_in[11];
  const float* sE    = (const float*)d_in[12];
  const float* mask  = (const float*)d_in[13];
  const float* smask = (const float*)d_in[14];
  const float* iw    = (const float*)d_in[15];
  const float* ib    = (const float*)d_in[16];
  const float* ow    = (const float*)d_in[17];
  const float* ob    = (const float*)d_in[18];

  float* wsf = (float*)d_ws;
  float4* p_rec  = (float4*)wsf;                    // N*N*4 floats
  float4* p_sens = (float4*)(wsf + NN * NN * 4);    // S*N*4 floats
  float* snum  = wsf + NN * NN * 4 + SS * NN * 4;   // B*N
  float* sden  = snum + BB * NN;
  float* vbuf0 = sden + BB * NN;
  float* vbuf1 = vbuf0 + BB * NN;

  float* fout = (float*)d_out;          // [B*M out][B*N v]

  prep_rec<<<(NN * NN) / 256, 256, 0, stream>>>(w, sg, mu, E, mask, p_rec);
  prep_sens<<<(SS * NN) / 256, 256, 0, stream>>>(sw, ssg, smu, sE, smask, iw, ib, p_sens);
  sensory_kernel<<<dim3(BB / BT, NN / JT), 512, 0, stream>>>(x, p_sens, snum, sden);

  const float* vin = state;
  for (int u = 0; u < UNFOLDS; ++u) {
    int lastf = (u == UNFOLDS - 1) ? 1 : 0;
    float* vo = lastf ? (fout + BB * MM) : ((u & 1) ? vbuf1 : vbuf0);
    unfold_kernel<<<dim3(BB / BT, NN / JT), 512, 0, stream>>>(
        vin, p_rec, snum, sden, gl, rp, cap, vo, ow, ob, fout, lastf);
    vin = vo;
  }
}

// Round 2
// 78.720 us; speedup vs baseline: 1.0584x; 1.0584x over previous
//
#include <hip/hip_runtime.h>

#define BB 512
#define NN 256
#define SS 128
#define MM 64
#define UNFOLDS 6
#define BT 4
#define JT 64

static constexpr float EPS_ = 1e-8f;
static constexpr float L2E = 1.4426950408889634f;

// ---------- precompute (merged): fold params into float4 {a, c, wE, wm} ----------
// gate = 1 / (1 + exp2(a*v + c)),  a = -sigma*log2e, c = sigma*mu*log2e
__global__ __launch_bounds__(256) void prep_kernel(
    const float* __restrict__ w, const float* __restrict__ sg,
    const float* __restrict__ mu, const float* __restrict__ E,
    const float* __restrict__ mask, float4* __restrict__ pr,
    const float* __restrict__ swv, const float* __restrict__ ssg,
    const float* __restrict__ smu, const float* __restrict__ sE,
    const float* __restrict__ smask, const float* __restrict__ iw,
    const float* __restrict__ ib, float4* __restrict__ ps) {
  int bid = blockIdx.x;
  if (bid < (NN * NN) / 256) {
    int idx = bid * 256 + threadIdx.x;
    float a = sg[idx] * L2E;
    float wm = w[idx] * mask[idx];
    pr[idx] = make_float4(-a, a * mu[idx], wm * E[idx], wm);
  } else {
    int idx = (bid - (NN * NN) / 256) * 256 + threadIdx.x;
    int s = idx >> 8;  // idx / NN
    float a = ssg[idx] * L2E;
    float wm = swv[idx] * smask[idx];
    // -a*(x*iw+ib) + a*mu = (-a*iw)*x + a*(mu - ib)
    ps[idx] = make_float4(-a * iw[s], a * (smu[idx] - ib[s]), wm * sE[idx], wm);
  }
}

// ---------- sensory aggregation: (B,S,N) -> snum/sden (B,N) ----------
// 512 threads: j = tid&63, pair = (tid>>6)&1 (2 batch-pairs), split = tid>>7 (4-way s)
__global__ __launch_bounds__(512) void sensory_kernel(
    const float* __restrict__ x, const float4* __restrict__ ps,
    float* __restrict__ snum, float* __restrict__ sden) {
  __shared__ float xt[BT][SS];       // 2 KiB
  __shared__ float4 red[3][128];     // 6 KiB
  int tid = threadIdx.x;
  int bbase = blockIdx.x * BT;
  int jbase = blockIdx.y * JT;
  // stage x tile: BT*SS = 512 floats, 512 threads -> 1 each
  xt[tid >> 7][tid & 127] = x[(bbase + (tid >> 7)) * SS + (tid & 127)];
  __syncthreads();
  int j = tid & 63;
  int pair = (tid >> 6) & 1;
  int split = tid >> 7;
  int b0 = 2 * pair, b1 = b0 + 1;
  float n0 = 0, d0 = 0, n1 = 0, d1 = 0;
  int s0 = split * (SS / 4);
#pragma unroll 8
  for (int ss = 0; ss < SS / 4; ++ss) {
    int s = s0 + ss;
    float4 p = ps[s * NN + jbase + j];
    float v0 = xt[b0][s], v1 = xt[b1][s];
    float e0 = __builtin_amdgcn_exp2f(fmaf(p.x, v0, p.y));
    float e1 = __builtin_amdgcn_exp2f(fmaf(p.x, v1, p.y));
    float g0 = __builtin_amdgcn_rcpf(1.0f + e0);
    float g1 = __builtin_amdgcn_rcpf(1.0f + e1);
    n0 = fmaf(p.z, g0, n0); d0 = fmaf(p.w, g0, d0);
    n1 = fmaf(p.z, g1, n1); d1 = fmaf(p.w, g1, d1);
  }
  int t = (pair << 6) | j;
  if (split) red[split - 1][t] = make_float4(n0, d0, n1, d1);
  __syncthreads();
  if (!split) {
    for (int k = 0; k < 3; ++k) {
      float4 r = red[k][t];
      n0 += r.x; d0 += r.y; n1 += r.z; d1 += r.w;
    }
    int jg = jbase + j;
    snum[(bbase + b0) * NN + jg] = n0; sden[(bbase + b0) * NN + jg] = d0;
    snum[(bbase + b1) * NN + jg] = n1; sden[(bbase + b1) * NN + jg] = d1;
  }
}

// ---------- one ODE unfold ----------
// 512 threads: j = tid&63, pair = (tid>>6)&1, split = tid>>7 (4-way i)
__global__ __launch_bounds__(512) void unfold_kernel(
    const float* __restrict__ vin, const float4* __restrict__ pr,
    const float* __restrict__ snum, const float* __restrict__ sden,
    const float* __restrict__ gl, const float* __restrict__ rp,
    const float* __restrict__ cap, float* __restrict__ vout,
    const float* __restrict__ ow, const float* __restrict__ ob,
    float* __restrict__ out, int last) {
  __shared__ float vt[BT][NN];   // 4 KiB
  __shared__ float4 red[3][128]; // 6 KiB
  int tid = threadIdx.x;
  int bbase = blockIdx.x * BT;
  int jbase = blockIdx.y * JT;
  // stage v tile: BT*NN = 1024 floats, 512 threads -> 2 each
  for (int k = 0; k < 2; ++k) {
    int idx = tid + k * 512;
    vt[idx >> 8][idx & 255] = vin[(bbase + (idx >> 8)) * NN + (idx & 255)];
  }
  __syncthreads();
  int j = tid & 63;
  int pair = (tid >> 6) & 1;
  int split = tid >> 7;
  int b0 = 2 * pair, b1 = b0 + 1;
  float n0 = 0, d0 = 0, n1 = 0, d1 = 0;
  int i0 = split * (NN / 4);
#pragma unroll 8
  for (int ii = 0; ii < NN / 4; ++ii) {
    int i = i0 + ii;
    float4 p = pr[i * NN + jbase + j];
    float v0 = vt[b0][i], v1 = vt[b1][i];
    float e0 = __builtin_amdgcn_exp2f(fmaf(p.x, v0, p.y));
    float e1 = __builtin_amdgcn_exp2f(fmaf(p.x, v1, p.y));
    float g0 = __builtin_amdgcn_rcpf(1.0f + e0);
    float g1 = __builtin_amdgcn_rcpf(1.0f + e1);
    n0 = fmaf(p.z, g0, n0); d0 = fmaf(p.w, g0, d0);
    n1 = fmaf(p.z, g1, n1); d1 = fmaf(p.w, g1, d1);
  }
  int t = (pair << 6) | j;
  if (split) red[split - 1][t] = make_float4(n0, d0, n1, d1);
  __syncthreads();
  if (!split) {
    for (int k = 0; k < 3; ++k) {
      float4 r = red[k][t];
      n0 += r.x; d0 += r.y; n1 += r.z; d1 += r.w;
    }
    int jg = jbase + j;
    float cmt = cap[jg] * (float)UNFOLDS;  // cap / (ELAPSED/UNFOLDS)
    float glv = gl[jg];
    float base = glv * rp[jg];
    int i0g = (bbase + b0) * NN + jg;
    int i1g = (bbase + b1) * NN + jg;
    float num0 = fmaf(cmt, vt[b0][jg], base) + n0 + snum[i0g];
    float den0 = cmt + glv + d0 + sden[i0g] + EPS_;
    float vn0 = num0 / den0;
    float num1 = fmaf(cmt, vt[b1][jg], base) + n1 + snum[i1g];
    float den1 = cmt + glv + d1 + sden[i1g] + EPS_;
    float vn1 = num1 / den1;
    vout[i0g] = vn0;
    vout[i1g] = vn1;
    if (last && jbase == 0) {  // jg < MM exactly when jbase==0 (JT==MM)
      out[(bbase + b0) * MM + jg] = fmaf(vn0, ow[jg], ob[jg]);
      out[(bbase + b1) * MM + jg] = fmaf(vn1, ow[jg], ob[jg]);
    }
  }
}

extern "C" void kernel_launch(void* const* d_in, const int* in_sizes, int n_in,
                              void* d_out, int out_size, void* d_ws, size_t ws_size,
                              hipStream_t stream) {
  const float* x     = (const float*)d_in[0];
  const float* state = (const float*)d_in[1];
  const float* gl    = (const float*)d_in[2];
  const float* rp    = (const float*)d_in[3];
  const float* cap   = (const float*)d_in[4];
  const float* w     = (const float*)d_in[5];
  const float* sg    = (const float*)d_in[6];
  const float* mu    = (const float*)d_in[7];
  const float* E     = (const float*)d_in[8];
  const float* sw    = (const float*)d_in[9];
  const float* ssg   = (const float*)d_in[10];
  const float* smu   = (const float*)d_in[11];
  const float* sE    = (const float*)d_in[12];
  const float* mask  = (const float*)d_in[13];
  const float* smask = (const float*)d_in[14];
  const float* iw    = (const float*)d_in[15];
  const float* ib    = (const float*)d_in[16];
  const float* ow    = (const float*)d_in[17];
  const float* ob    = (const float*)d_in[18];

  float* wsf = (float*)d_ws;
  float4* p_rec  = (float4*)wsf;                    // N*N*4 floats
  float4* p_sens = (float4*)(wsf + NN * NN * 4);    // S*N*4 floats
  float* snum  = wsf + NN * NN * 4 + SS * NN * 4;   // B*N
  float* sden  = snum + BB * NN;
  float* vbuf0 = sden + BB * NN;
  float* vbuf1 = vbuf0 + BB * NN;

  float* fout = (float*)d_out;          // [B*M out][B*N v]

  prep_kernel<<<(NN * NN + SS * NN) / 256, 256, 0, stream>>>(
      w, sg, mu, E, mask, p_rec, sw, ssg, smu, sE, smask, iw, ib, p_sens);
  sensory_kernel<<<dim3(BB / BT, NN / JT), 512, 0, stream>>>(x, p_sens, snum, sden);

  const float* vin = state;
  for (int u = 0; u < UNFOLDS; ++u) {
    int lastf = (u == UNFOLDS - 1) ? 1 : 0;
    float* vo = lastf ? (fout + BB * MM) : ((u & 1) ? vbuf1 : vbuf0);
    unfold_kernel<<<dim3(BB / BT, NN / JT), 512, 0, stream>>>(
        vin, p_rec, snum, sden, gl, rp, cap, vo, ow, ob, fout, lastf);
    vin = vo;
  }
}

// Round 3
// 76.052 us; speedup vs baseline: 1.0955x; 1.0351x over previous
//
#include <hip/hip_runtime.h>

#define BB 512
#define NN 256
#define SS 128
#define MM 64
#define UNFOLDS 6
#define BT 4      // sensory batch tile
#define JT 64     // sensory j tile
#define BT2 16    // unfold batch tile
#define JT2 32    // unfold j tile

static constexpr float EPS_ = 1e-8f;
static constexpr float L2E = 1.4426950408889634f;

// ---------- precompute (merged): fold params into float4 {a, c, wE, wm} ----------
// gate = 1 / (1 + exp2(a*v + c)),  a = -sigma*log2e, c = sigma*mu*log2e
__global__ __launch_bounds__(256) void prep_kernel(
    const float* __restrict__ w, const float* __restrict__ sg,
    const float* __restrict__ mu, const float* __restrict__ E,
    const float* __restrict__ mask, float4* __restrict__ pr,
    const float* __restrict__ swv, const float* __restrict__ ssg,
    const float* __restrict__ smu, const float* __restrict__ sE,
    const float* __restrict__ smask, const float* __restrict__ iw,
    const float* __restrict__ ib, float4* __restrict__ ps) {
  int bid = blockIdx.x;
  if (bid < (NN * NN) / 256) {
    int idx = bid * 256 + threadIdx.x;
    float a = sg[idx] * L2E;
    float wm = w[idx] * mask[idx];
    pr[idx] = make_float4(-a, a * mu[idx], wm * E[idx], wm);
  } else {
    int idx = (bid - (NN * NN) / 256) * 256 + threadIdx.x;
    int s = idx >> 8;  // idx / NN
    float a = ssg[idx] * L2E;
    float wm = swv[idx] * smask[idx];
    // -a*(x*iw+ib) + a*mu = (-a*iw)*x + a*(mu - ib)
    ps[idx] = make_float4(-a * iw[s], a * (smu[idx] - ib[s]), wm * sE[idx], wm);
  }
}

// ---------- sensory aggregation: (B,S,N) -> snum/sden (B,N) ----------
// 512 threads: j = tid&63, pair = (tid>>6)&1 (2 batch-pairs), split = tid>>7 (4-way s)
__global__ __launch_bounds__(512) void sensory_kernel(
    const float* __restrict__ x, const float4* __restrict__ ps,
    float* __restrict__ snum, float* __restrict__ sden) {
  __shared__ float xt[BT][SS];       // 2 KiB
  __shared__ float4 red[3][128];     // 6 KiB
  int tid = threadIdx.x;
  int bbase = blockIdx.x * BT;
  int jbase = blockIdx.y * JT;
  xt[tid >> 7][tid & 127] = x[(bbase + (tid >> 7)) * SS + (tid & 127)];
  __syncthreads();
  int j = tid & 63;
  int pair = (tid >> 6) & 1;
  int split = tid >> 7;
  int b0 = 2 * pair, b1 = b0 + 1;
  float n0 = 0, d0 = 0, n1 = 0, d1 = 0;
  int s0 = split * (SS / 4);
#pragma unroll 8
  for (int ss = 0; ss < SS / 4; ++ss) {
    int s = s0 + ss;
    float4 p = ps[s * NN + jbase + j];
    float v0 = xt[b0][s], v1 = xt[b1][s];
    float e0 = __builtin_amdgcn_exp2f(fmaf(p.x, v0, p.y));
    float e1 = __builtin_amdgcn_exp2f(fmaf(p.x, v1, p.y));
    float g0 = __builtin_amdgcn_rcpf(1.0f + e0);
    float g1 = __builtin_amdgcn_rcpf(1.0f + e1);
    n0 = fmaf(p.z, g0, n0); d0 = fmaf(p.w, g0, d0);
    n1 = fmaf(p.z, g1, n1); d1 = fmaf(p.w, g1, d1);
  }
  int t = (pair << 6) | j;
  if (split) red[split - 1][t] = make_float4(n0, d0, n1, d1);
  __syncthreads();
  if (!split) {
    for (int k = 0; k < 3; ++k) {
      float4 r = red[k][t];
      n0 += r.x; d0 += r.y; n1 += r.z; d1 += r.w;
    }
    int jg = jbase + j;
    snum[(bbase + b0) * NN + jg] = n0; sden[(bbase + b0) * NN + jg] = d0;
    snum[(bbase + b1) * NN + jg] = n1; sden[(bbase + b1) * NN + jg] = d1;
  }
}

// ---------- one ODE unfold ----------
// 1024 threads: j = tid&31, quad = (tid>>5)&3 (4 batches each), split = tid>>7 (8-way i)
// grid (BB/BT2=32, NN/JT2=8) = 256 blocks = 1 block/CU, 4 waves/SIMD
__global__ __launch_bounds__(1024) void unfold_kernel(
    const float* __restrict__ vin, const float4* __restrict__ pr,
    const float* __restrict__ snum, const float* __restrict__ sden,
    const float* __restrict__ gl, const float* __restrict__ rp,
    const float* __restrict__ cap, float* __restrict__ vout,
    const float* __restrict__ ow, const float* __restrict__ ob,
    float* __restrict__ out, int last) {
  __shared__ float vt[BT2][NN];     // 16 KiB
  __shared__ float4 redN[7 * 128];  // 14 KiB
  __shared__ float4 redD[7 * 128];  // 14 KiB
  int tid = threadIdx.x;
  int bbase = blockIdx.x * BT2;
  int jbase = blockIdx.y * JT2;
  // stage v tile: BT2*NN = 4096 floats, 1024 threads -> 1 float4 each
  ((float4*)vt)[tid] = ((const float4*)(vin + bbase * NN))[tid];
  __syncthreads();
  int j = tid & 31;
  int quad = (tid >> 5) & 3;
  int split = tid >> 7;
  int b0 = quad * 4;
  int jcol = jbase + j;
  float n[4] = {0, 0, 0, 0}, d[4] = {0, 0, 0, 0};
  const float4* prow = pr + split * 32 * NN + jcol;
#pragma unroll 4
  for (int ii = 0; ii < 32; ++ii) {
    int i = split * 32 + ii;
    float4 p = prow[ii * NN];
#pragma unroll
    for (int q = 0; q < 4; ++q) {
      float v = vt[b0 + q][i];
      float e = __builtin_amdgcn_exp2f(fmaf(p.x, v, p.y));
      float g = __builtin_amdgcn_rcpf(1.0f + e);
      n[q] = fmaf(p.z, g, n[q]);
      d[q] = fmaf(p.w, g, d[q]);
    }
  }
  int t = tid & 127;
  if (split) {
    redN[(split - 1) * 128 + t] = make_float4(n[0], n[1], n[2], n[3]);
    redD[(split - 1) * 128 + t] = make_float4(d[0], d[1], d[2], d[3]);
  }
  __syncthreads();
  if (split == 0) {
#pragma unroll
    for (int k = 0; k < 7; ++k) {
      float4 rn = redN[k * 128 + t];
      float4 rd = redD[k * 128 + t];
      n[0] += rn.x; n[1] += rn.y; n[2] += rn.z; n[3] += rn.w;
      d[0] += rd.x; d[1] += rd.y; d[2] += rd.z; d[3] += rd.w;
    }
    float cmt = cap[jcol] * (float)UNFOLDS;
    float glv = gl[jcol];
    float base = glv * rp[jcol];
#pragma unroll
    for (int q = 0; q < 4; ++q) {
      int b = bbase + b0 + q;
      int ig = b * NN + jcol;
      float num = fmaf(cmt, vt[b0 + q][jcol], base) + n[q] + snum[ig];
      float den = cmt + glv + d[q] + sden[ig] + EPS_;
      float vn = num * __builtin_amdgcn_rcpf(den);
      vout[ig] = vn;
      if (last && jcol < MM) out[b * MM + jcol] = fmaf(vn, ow[jcol], ob[jcol]);
    }
  }
}

extern "C" void kernel_launch(void* const* d_in, const int* in_sizes, int n_in,
                              void* d_out, int out_size, void* d_ws, size_t ws_size,
                              hipStream_t stream) {
  const float* x     = (const float*)d_in[0];
  const float* state = (const float*)d_in[1];
  const float* gl    = (const float*)d_in[2];
  const float* rp    = (const float*)d_in[3];
  const float* cap   = (const float*)d_in[4];
  const float* w     = (const float*)d_in[5];
  const float* sg    = (const float*)d_in[6];
  const float* mu    = (const float*)d_in[7];
  const float* E     = (const float*)d_in[8];
  const float* sw    = (const float*)d_in[9];
  const float* ssg   = (const float*)d_in[10];
  const float* smu   = (const float*)d_in[11];
  const float* sE    = (const float*)d_in[12];
  const float* mask  = (const float*)d_in[13];
  const float* smask = (const float*)d_in[14];
  const float* iw    = (const float*)d_in[15];
  const float* ib    = (const float*)d_in[16];
  const float* ow    = (const float*)d_in[17];
  const float* ob    = (const float*)d_in[18];

  float* wsf = (float*)d_ws;
  float4* p_rec  = (float4*)wsf;                    // N*N*4 floats
  float4* p_sens = (float4*)(wsf + NN * NN * 4);    // S*N*4 floats
  float* snum  = wsf + NN * NN * 4 + SS * NN * 4;   // B*N
  float* sden  = snum + BB * NN;
  float* vbuf0 = sden + BB * NN;
  float* vbuf1 = vbuf0 + BB * NN;

  float* fout = (float*)d_out;          // [B*M out][B*N v]

  prep_kernel<<<(NN * NN + SS * NN) / 256, 256, 0, stream>>>(
      w, sg, mu, E, mask, p_rec, sw, ssg, smu, sE, smask, iw, ib, p_sens);
  sensory_kernel<<<dim3(BB / BT, NN / JT), 512, 0, stream>>>(x, p_sens, snum, sden);

  const float* vin = state;
  for (int u = 0; u < UNFOLDS; ++u) {
    int lastf = (u == UNFOLDS - 1) ? 1 : 0;
    float* vo = lastf ? (fout + BB * MM) : ((u & 1) ? vbuf1 : vbuf0);
    unfold_kernel<<<dim3(BB / BT2, NN / JT2), 1024, 0, stream>>>(
        vin, p_rec, snum, sden, gl, rp, cap, vo, ow, ob, fout, lastf);
    vin = vo;
  }
}